// Round 9
// baseline (101.822 us; speedup 1.0000x reference)
//
#include <hip/hip_runtime.h>

#define BDIM 2
#define SDIM 4096
#define HIDDEN 2048
#define NH 4
#define DD 64
#define RR 32
#define NG_COLS 192
constexpr float LN_EPS = 1e-5f;

typedef _Float16 half8 __attribute__((ext_vector_type(8)));   // 8 f16 = 4 VGPRs
typedef __attribute__((ext_vector_type(4))) float f32x4;

// async global -> LDS, 16 B per lane (wave-uniform LDS base + lane*16)
__device__ __forceinline__ void gload_lds16(const void* g, void* l) {
    __builtin_amdgcn_global_load_lds(
        (const __attribute__((address_space(1))) void*)g,
        (__attribute__((address_space(3))) void*)l, 16, 0, 0);
}

// ---------------------------------------------------------------------------
// split_hs: hs f32 [M,2048] -> hs2 f16 [M,2048], pre-swizzled per row
// (16B-slot XOR with m&7) so linear global_load_lds + XOR ds_read is
// conflict-free (rule #21). One thread per 8-elem slot. M = 8192.
// ---------------------------------------------------------------------------
__global__ __launch_bounds__(256) void split_hs(
    const float* __restrict__ hs, _Float16* __restrict__ hs2)
{
    const int idx  = blockIdx.x * 256 + threadIdx.x;
    const int m    = idx >> 8;          // 256 slots per row
    const int slot = idx & 255;
    const float4 v0 = *reinterpret_cast<const float4*>(&hs[(size_t)m * HIDDEN + slot * 8]);
    const float4 v1 = *reinterpret_cast<const float4*>(&hs[(size_t)m * HIDDEN + slot * 8 + 4]);
    _Float16 o[8];
    o[0] = (_Float16)v0.x; o[1] = (_Float16)v0.y;
    o[2] = (_Float16)v0.z; o[3] = (_Float16)v0.w;
    o[4] = (_Float16)v1.x; o[5] = (_Float16)v1.y;
    o[6] = (_Float16)v1.z; o[7] = (_Float16)v1.w;
    const int eoff = (slot * 8) ^ ((m & 7) << 3);
    *reinterpret_cast<half8*>(&hs2[(size_t)m * HIDDEN + eoff]) =
        *reinterpret_cast<half8*>(o);
}

// ---------------------------------------------------------------------------
// prep_w2: Wt2 f16 [384][2048] transposed k-contiguous, pre-swizzled.
// NEW n-order (k isolated in one wave's 96-col span):
//   n   0..255 : Wq col n            (q heads 0..3)
//   n 256..287 : zero pad
//   n 288..351 : Wk col n-288        (k)
//   n 352..355 : Ww col n-352        (w)
//   n 356..383 : zero pad
// Grid (32, 6), 256 threads.
// ---------------------------------------------------------------------------
__global__ __launch_bounds__(256) void prep_w2(
    const float* __restrict__ Wq, const float* __restrict__ Wk,
    const float* __restrict__ Ww, _Float16* __restrict__ Wt2)
{
    __shared__ float T[64][65];
    const int k0 = blockIdx.x * 64, n0 = blockIdx.y * 64;
    const int tid = threadIdx.x;
    {
        const int kr = tid >> 2;
        const int nq = (tid & 3) * 16;
        const int gk = k0 + kr;
        #pragma unroll
        for (int c = 0; c < 16; ++c) {
            const int n = n0 + nq + c;
            float v;
            if (n < 256)      v = Wq[(size_t)gk * 256 + n];
            else if (n < 288) v = 0.f;
            else if (n < 352) v = Wk[(size_t)gk * 64 + (n - 288)];
            else if (n < 356) v = Ww[(size_t)gk * NH + (n - 352)];
            else              v = 0.f;
            T[kr][nq + c] = v;
        }
    }
    __syncthreads();
    {
        const int nr = tid >> 2;
        const int kc = (tid & 3) * 16;
        const int n  = n0 + nr;
        #pragma unroll
        for (int s = 0; s < 2; ++s) {
            const int kb = kc + s * 8;
            _Float16 e[8];
            #pragma unroll
            for (int t = 0; t < 8; ++t) e[t] = (_Float16)T[kb + t][nr];
            const int eoff = (k0 + kb) ^ ((nr & 7) << 3);
            *reinterpret_cast<half8*>(&Wt2[(size_t)n * HIDDEN + eoff]) =
                *reinterpret_cast<half8*>(e);
        }
    }
}

// ---------------------------------------------------------------------------
// proj_mfma v4: grid (M/64 = 128, 2 ng) = 256 blocks (1/CU), 256 threads.
// Block tile 64M x 192N (ng*192 col base). BK=64, double-buffered 64 KB LDS,
// STAGE(next) issued before compute(current) -> load latency hides under MFMA.
// 4 waves in 2M x 2N; wave tile 32 x 96 (acc[2][6]): 8 ds_read_b128 / 12 MFMA.
// ng=1,wn=1 holds k (cols 288..351) -> intra-wave LN; w at 352..355.
// NOTE: grid.x MUST be M/64 = 128 (R8 crash was 256 here -> OOB writes).
// ---------------------------------------------------------------------------
__global__ __launch_bounds__(256) void proj_mfma(
    const _Float16* __restrict__ hs2, const _Float16* __restrict__ Wt2,
    const float* __restrict__ cosb, const float* __restrict__ sinb,
    const float* __restrict__ gamma, const float* __restrict__ beta,
    _Float16* __restrict__ qout, _Float16* __restrict__ kout,
    float* __restrict__ wout)
{
    __shared__ _Float16 Asm[2][64 * 64];        // 16 KB
    __shared__ _Float16 Bsm[2][NG_COLS * 64];   // 48 KB

    const int m0   = blockIdx.x * 64;
    const int ng   = blockIdx.y;
    const int tid  = threadIdx.x;
    const int wave = tid >> 6, lane = tid & 63;
    const int wm = wave >> 1, wn = wave & 1;
    const int lr = lane & 15, lh = lane >> 4;

    f32x4 acc[2][6];
    #pragma unroll
    for (int i = 0; i < 2; ++i)
        #pragma unroll
        for (int j = 0; j < 6; ++j)
            acc[i][j] = (f32x4){0.f, 0.f, 0.f, 0.f};

    // staging: slot s -> row s>>3, 16B chunk s&7. A: 512 slots, B: 1536 slots.
    #define STAGE(pp, kk) do {                                                  \
        _Pragma("unroll")                                                       \
        for (int s2 = 0; s2 < 2; ++s2) {                                        \
            const int slot = tid + s2 * 256;                                    \
            gload_lds16(hs2 + (size_t)(m0 + (slot >> 3)) * HIDDEN               \
                            + (slot & 7) * 8 + (kk),                            \
                        &Asm[pp][slot * 8]);                                    \
        }                                                                       \
        _Pragma("unroll")                                                       \
        for (int s6 = 0; s6 < 6; ++s6) {                                        \
            const int slot = tid + s6 * 256;                                    \
            gload_lds16(Wt2 + (size_t)(ng * NG_COLS + (slot >> 3)) * HIDDEN     \
                            + (slot & 7) * 8 + (kk),                            \
                        &Bsm[pp][slot * 8]);                                    \
        }                                                                       \
    } while (0)

    STAGE(0, 0);
    __syncthreads();

    int p = 0;
    for (int t = 0; t < HIDDEN / 64; ++t) {
        if (t < HIDDEN / 64 - 1) STAGE(p ^ 1, (t + 1) * 64);

        #pragma unroll
        for (int ks = 0; ks < 2; ++ks) {
            half8 av[2], bv[6];
            #pragma unroll
            for (int i = 0; i < 2; ++i) {
                const int arow = wm * 32 + i * 16 + lr;
                const int aoff = (arow * 64 + ks * 32 + lh * 8) ^ ((arow & 7) << 3);
                av[i] = *reinterpret_cast<const half8*>(&Asm[p][aoff]);
            }
            #pragma unroll
            for (int j = 0; j < 6; ++j) {
                const int brow = wn * 96 + j * 16 + lr;
                const int boff = (brow * 64 + ks * 32 + lh * 8) ^ ((brow & 7) << 3);
                bv[j] = *reinterpret_cast<const half8*>(&Bsm[p][boff]);
            }
            #pragma unroll
            for (int i = 0; i < 2; ++i)
                #pragma unroll
                for (int j = 0; j < 6; ++j)
                    acc[i][j] = __builtin_amdgcn_mfma_f32_16x16x32_f16(
                        av[i], bv[j], acc[i][j], 0, 0, 0);
        }
        __syncthreads();
        p ^= 1;
    }
    #undef STAGE

    // ---- epilogue. C/D: col = lr, row = wm*32 + i*16 + lh*4 + r.
    // Wave's global col base c0 = ng*192 + wn*96; frag j at c0 + j*16.
    auto store_q = [&](int j, int basec) {
        #pragma unroll
        for (int i = 0; i < 2; ++i)
            #pragma unroll
            for (int r = 0; r < 4; ++r) {
                const int m = m0 + wm * 32 + i * 16 + lh * 4 + r;
                const int sw = (m & 7) << 3;
                qout[(size_t)m * 256 + ((basec + lr) ^ sw)] = (_Float16)acc[i][j][r];
            }
    };
    auto store_q_rope = [&](int j, int basec) {
        #pragma unroll
        for (int i = 0; i < 2; ++i)
            #pragma unroll
            for (int r = 0; r < 4; ++r) {
                const int m = m0 + wm * 32 + i * 16 + lh * 4 + r;
                const float x0 = acc[i][j][r], x1 = acc[i][j + 1][r];
                const float c0 = cosb[(size_t)m * RR + lr];
                const float s0 = sinb[(size_t)m * RR + lr];
                const float c1 = cosb[(size_t)m * RR + 16 + lr];
                const float s1 = sinb[(size_t)m * RR + 16 + lr];
                const int sw = (m & 7) << 3;
                const size_t rowb = (size_t)m * 256;
                qout[rowb + ((basec + lr) ^ sw)]      = (_Float16)(x0 * c0 - x1 * s0);
                qout[rowb + ((basec + 16 + lr) ^ sw)] = (_Float16)(x1 * c1 + x0 * s1);
            }
    };

    if (ng == 0) {
        if (wn == 0) {        // cols 0..95: head0 (rope d0..31, pass d32..63), head1 d0..31
            store_q_rope(0, 0);  store_q(2, 32);  store_q(3, 48);  store_q_rope(4, 64);
        } else {              // cols 96..191: head1 d32..63, head2 (rope d0..31, pass)
            store_q(0, 96);  store_q(1, 112);  store_q_rope(2, 128);
            store_q(4, 160); store_q(5, 176);
        }
    } else {
        if (wn == 0) {        // cols 192..255: head3; cols 256..287 pad (frags 4,5 dropped)
            store_q_rope(0, 192);  store_q(2, 224);  store_q(3, 240);
        } else {
            // frags 0..3 = k (Wt2 cols 288..351): LayerNorm over d=0..63, then RoPE
            float g[4], bb[4];
            #pragma unroll
            for (int jj = 0; jj < 4; ++jj) {
                g[jj] = gamma[jj * 16 + lr]; bb[jj] = beta[jj * 16 + lr];
            }
            #pragma unroll
            for (int i = 0; i < 2; ++i)
                #pragma unroll
                for (int r = 0; r < 4; ++r) {
                    float t1 = 0.f, t2 = 0.f;
                    #pragma unroll
                    for (int jj = 0; jj < 4; ++jj) {
                        const float a = acc[i][jj][r];
                        t1 += a; t2 += a * a;
                    }
                    #pragma unroll
                    for (int msk = 1; msk < 16; msk <<= 1) {
                        t1 += __shfl_xor(t1, msk, 64);
                        t2 += __shfl_xor(t2, msk, 64);
                    }
                    const float mu  = t1 * (1.f / 64.f);
                    const float var = t2 * (1.f / 64.f) - mu * mu;
                    const float rs  = rsqrtf(var + LN_EPS);
                    const int m = m0 + wm * 32 + i * 16 + lh * 4 + r;
                    float x[4];
                    #pragma unroll
                    for (int jj = 0; jj < 4; ++jj)
                        x[jj] = (acc[i][jj][r] - mu) * rs * g[jj] + bb[jj];
                    const float c0 = cosb[(size_t)m * RR + lr];
                    const float s0 = sinb[(size_t)m * RR + lr];
                    const float c1 = cosb[(size_t)m * RR + 16 + lr];
                    const float s1 = sinb[(size_t)m * RR + 16 + lr];
                    const float y0 = x[0] * c0 - x[1] * s0;
                    const float y1 = x[1] * c1 + x[0] * s1;
                    const size_t base = (size_t)m * DD + lr;
                    kout[base]      = (_Float16)y0;
                    kout[base + 16] = (_Float16)y1;
                    kout[base + 32] = (_Float16)x[2];
                    kout[base + 48] = (_Float16)x[3];
                }
            // frag 4 = w (cols 352..355)
            if (lr < NH) {
                #pragma unroll
                for (int i = 0; i < 2; ++i)
                    #pragma unroll
                    for (int r = 0; r < 4; ++r) {
                        const int m = m0 + wm * 32 + i * 16 + lh * 4 + r;
                        wout[(size_t)m * NH + lr] = acc[i][4][r];
                    }
            }
            // frag 5 = pad, dropped
        }
    }
}

// ---------------------------------------------------------------------------
// score (R6 form, measured 38 us): s = mfma(Q,K); C/D col=k, row=q; scalar
// stores (4 rows x 64B segments/inst). Grid (8 k-chunks, 64 q-tiles, B);
// Q-tile staged in LDS once via gload_lds; K frags 2-deep register prefetch.
// ---------------------------------------------------------------------------
__global__ __launch_bounds__(256) void score_kernel(
    const _Float16* __restrict__ qb, const _Float16* __restrict__ kb,
    const float* __restrict__ wr, float* __restrict__ out)
{
    __shared__ _Float16 Qlds[64 * 256];   // 32 KB, swizzled slots
    __shared__ float Wlds[64 * 4];        // 1 KB

    const int kc  = blockIdx.x;          // 512-col k chunk
    const int q0  = blockIdx.y * 64;
    const int b   = blockIdx.z;
    const int tid = threadIdx.x;
    const int wave = tid >> 6, lane = tid & 63;
    const int wm = wave >> 1, wn = wave & 1;
    const int lr = lane & 15, lh = lane >> 4;
    const int kbase = kc * 512;

    #pragma unroll
    for (int i = 0; i < 8; ++i) {
        const int id = i * 256 + tid;
        gload_lds16(qb + (size_t)(b * SDIM + q0 + (id >> 5)) * 256 + (id & 31) * 8,
                    Qlds + id * 8);
    }
    Wlds[tid] = wr[(size_t)(b * SDIM + q0) * NH + tid];
    __syncthreads();

    f32x4 wreg[2][4];
    #pragma unroll
    for (int i = 0; i < 2; ++i)
        #pragma unroll
        for (int r = 0; r < 4; ++r)
            wreg[i][r] = *reinterpret_cast<const f32x4*>(
                &Wlds[(wm * 32 + i * 16 + lh * 4 + r) * 4]);

    const size_t krow_base = (size_t)(b * SDIM + kbase + wn * 32);
    #define LOADK(dst, st)                                                      \
        _Pragma("unroll")                                                       \
        for (int j = 0; j < 2; ++j)                                             \
            _Pragma("unroll")                                                   \
            for (int ks = 0; ks < 2; ++ks)                                      \
                dst[j][ks] = *reinterpret_cast<const half8*>(                   \
                    &kb[(krow_base + (st) * 64 + j * 16 + lr) * DD + ks * 32 + lh * 8]);

    half8 kcur[2][2], knx[2][2];
    LOADK(kcur, 0)

    for (int st = 0; st < 8; ++st) {
        if (st < 7) { LOADK(knx, st + 1) }

        f32x4 o[2][2];
        #pragma unroll
        for (int i = 0; i < 2; ++i)
            #pragma unroll
            for (int j = 0; j < 2; ++j)
                o[i][j] = (f32x4){0.f, 0.f, 0.f, 0.f};

        #pragma unroll
        for (int h = 0; h < NH; ++h) {
            half8 qf[2][2];
            #pragma unroll
            for (int i = 0; i < 2; ++i)
                #pragma unroll
                for (int ks = 0; ks < 2; ++ks) {
                    const int row  = wm * 32 + i * 16 + lr;
                    const int slot = (h * 8 + ks * 4 + lh) ^ (row & 7);
                    qf[i][ks] = *reinterpret_cast<const half8*>(
                        &Qlds[row * 256 + slot * 8]);
                }
            f32x4 s[2][2];
            #pragma unroll
            for (int i = 0; i < 2; ++i)
                #pragma unroll
                for (int j = 0; j < 2; ++j)
                    s[i][j] = (f32x4){0.f, 0.f, 0.f, 0.f};
            #pragma unroll
            for (int ks = 0; ks < 2; ++ks)
                #pragma unroll
                for (int i = 0; i < 2; ++i)
                    #pragma unroll
                    for (int j = 0; j < 2; ++j)
                        s[i][j] = __builtin_amdgcn_mfma_f32_16x16x32_f16(
                            qf[i][ks], kcur[j][ks], s[i][j], 0, 0, 0);
            #pragma unroll
            for (int i = 0; i < 2; ++i)
                #pragma unroll
                for (int j = 0; j < 2; ++j)
                    #pragma unroll
                    for (int r = 0; r < 4; ++r)
                        o[i][j][r] += wreg[i][r][h] * fmaxf(s[i][j][r], 0.f);
        }

        #pragma unroll
        for (int i = 0; i < 2; ++i)
            #pragma unroll
            for (int r = 0; r < 4; ++r)
                #pragma unroll
                for (int j = 0; j < 2; ++j)
                    out[(size_t)(b * SDIM + q0 + wm * 32 + i * 16 + lh * 4 + r) * SDIM
                        + kbase + st * 64 + wn * 32 + j * 16 + lr] = o[i][j][r];

        #pragma unroll
        for (int j = 0; j < 2; ++j)
            #pragma unroll
            for (int ks = 0; ks < 2; ++ks)
                kcur[j][ks] = knx[j][ks];
    }
    #undef LOADK
}

// ---------------------------------------------------------------------------
extern "C" void kernel_launch(void* const* d_in, const int* in_sizes, int n_in,
                              void* d_out, int out_size, void* d_ws, size_t ws_size,
                              hipStream_t stream) {
    const float* hs    = (const float*)d_in[0];
    const float* cosb  = (const float*)d_in[1];
    const float* sinb  = (const float*)d_in[2];
    const float* Wq    = (const float*)d_in[3];
    const float* Wk    = (const float*)d_in[4];
    const float* Ww    = (const float*)d_in[5];
    const float* gamma = (const float*)d_in[6];
    const float* beta  = (const float*)d_in[7];
    float* out = (float*)d_out;

    // hs2 (33.5 MB f16) lives in d_out; dead after proj, overwritten by score.
    _Float16* hs2 = (_Float16*)d_out;

    char* wsb = (char*)d_ws;
    _Float16* qb  = (_Float16*)wsb;                                   // [M,256] f16
    _Float16* kb  = (_Float16*)(wsb + (size_t)BDIM * SDIM * 256 * 2); // [M,64] f16
    float*    ww  = (float*)(wsb + (size_t)BDIM * SDIM * 256 * 2
                                  + (size_t)BDIM * SDIM * DD * 2);
    _Float16* Wt2 = (_Float16*)(wsb + (size_t)BDIM * SDIM * 256 * 2
                                     + (size_t)BDIM * SDIM * DD * 2
                                     + (size_t)BDIM * SDIM * NH * 4);

    prep_w2<<<dim3(HIDDEN / 64, 6), 256, 0, stream>>>(Wq, Wk, Ww, Wt2);

    split_hs<<<(BDIM * SDIM * (HIDDEN / 8)) / 256, 256, 0, stream>>>(hs, hs2);

    // grid.x = M/64 = 128 (NOT 256 — R8's OOB bug)
    proj_mfma<<<dim3((BDIM * SDIM) / 64, 2), 256, 0, stream>>>(
        hs2, Wt2, cosb, sinb, gamma, beta, qb, kb, ww);

    score_kernel<<<dim3(SDIM / 512, SDIM / 64, BDIM), 256, 0, stream>>>(
        qb, kb, ww, out);
}

// Round 10
// 85.444 us; speedup vs baseline: 1.1917x; 1.1917x over previous
//
#include <hip/hip_runtime.h>

#define BDIM 2
#define SDIM 4096
#define HIDDEN 2048
#define NH 4
#define DD 64
#define RR 32
constexpr float LN_EPS = 1e-5f;

typedef _Float16 half8 __attribute__((ext_vector_type(8)));   // 8 f16 = 4 VGPRs
typedef __attribute__((ext_vector_type(4))) float f32x4;

// async global -> LDS, 16 B per lane (wave-uniform LDS base + lane*16)
__device__ __forceinline__ void gload_lds16(const void* g, void* l) {
    __builtin_amdgcn_global_load_lds(
        (const __attribute__((address_space(1))) void*)g,
        (__attribute__((address_space(3))) void*)l, 16, 0, 0);
}

// ---------------------------------------------------------------------------
// split_hs: hs f32 [M,2048] -> hs2 f16 [M,2048], pre-swizzled per row
// (16B-slot XOR with m&7) so linear global_load_lds + XOR ds_read is
// conflict-free (rule #21). One thread per 8-elem slot. M = 8192.
// ---------------------------------------------------------------------------
__global__ __launch_bounds__(256) void split_hs(
    const float* __restrict__ hs, _Float16* __restrict__ hs2)
{
    const int idx  = blockIdx.x * 256 + threadIdx.x;
    const int m    = idx >> 8;          // 256 slots per row
    const int slot = idx & 255;
    const float4 v0 = *reinterpret_cast<const float4*>(&hs[(size_t)m * HIDDEN + slot * 8]);
    const float4 v1 = *reinterpret_cast<const float4*>(&hs[(size_t)m * HIDDEN + slot * 8 + 4]);
    _Float16 o[8];
    o[0] = (_Float16)v0.x; o[1] = (_Float16)v0.y;
    o[2] = (_Float16)v0.z; o[3] = (_Float16)v0.w;
    o[4] = (_Float16)v1.x; o[5] = (_Float16)v1.y;
    o[6] = (_Float16)v1.z; o[7] = (_Float16)v1.w;
    const int eoff = (slot * 8) ^ ((m & 7) << 3);
    *reinterpret_cast<half8*>(&hs2[(size_t)m * HIDDEN + eoff]) =
        *reinterpret_cast<half8*>(o);
}

// ---------------------------------------------------------------------------
// prep_w2 (R6 map): Wt2 f16 [384][2048] transposed k-contiguous, pre-swizzled.
// n-order: q 0..255, k 256..319, w 320..323, zeros to 383. Grid (32, 6).
// ---------------------------------------------------------------------------
__global__ __launch_bounds__(256) void prep_w2(
    const float* __restrict__ Wq, const float* __restrict__ Wk,
    const float* __restrict__ Ww, _Float16* __restrict__ Wt2)
{
    __shared__ float T[64][65];
    const int k0 = blockIdx.x * 64, n0 = blockIdx.y * 64;
    const int tid = threadIdx.x;
    {
        const int kr = tid >> 2;
        const int nq = (tid & 3) * 16;
        const int gk = k0 + kr;
        #pragma unroll
        for (int c = 0; c < 16; ++c) {
            const int n = n0 + nq + c;
            float v;
            if (n < 256)      v = Wq[(size_t)gk * 256 + n];
            else if (n < 320) v = Wk[(size_t)gk * 64 + (n - 256)];
            else if (n < 324) v = Ww[(size_t)gk * NH + (n - 320)];
            else              v = 0.f;
            T[kr][nq + c] = v;
        }
    }
    __syncthreads();
    {
        const int nr = tid >> 2;
        const int kc = (tid & 3) * 16;
        const int n  = n0 + nr;
        #pragma unroll
        for (int s = 0; s < 2; ++s) {
            const int kb = kc + s * 8;
            _Float16 e[8];
            #pragma unroll
            for (int t = 0; t < 8; ++t) e[t] = (_Float16)T[kb + t][nr];
            const int eoff = (k0 + kb) ^ ((nr & 7) << 3);
            *reinterpret_cast<half8*>(&Wt2[(size_t)n * HIDDEN + eoff]) =
                *reinterpret_cast<half8*>(e);
        }
    }
}

// ---------------------------------------------------------------------------
// proj_mfma (R6 structure, measured 21 us): 128M x 64N, BK=128, K=2048,
// grid (64,6), 4 waves of 32M x 64N, 48 KB LDS -> 3 blocks/CU (12 waves:
// the occupancy that hides the pre-barrier vmcnt drain — R9's 64KB/1-block
// variant exposed it and regressed). q-epilogue writes qout PRE-SWIZZLED.
// ---------------------------------------------------------------------------
__global__ __launch_bounds__(256) void proj_mfma(
    const _Float16* __restrict__ hs2, const _Float16* __restrict__ Wt2,
    const float* __restrict__ cosb, const float* __restrict__ sinb,
    const float* __restrict__ gamma, const float* __restrict__ beta,
    _Float16* __restrict__ qout, _Float16* __restrict__ kout,
    float* __restrict__ wout)
{
    __shared__ _Float16 Asm[128 * 128];   // 32 KB
    __shared__ _Float16 Bsm[64 * 128];    // 16 KB

    const int m0   = blockIdx.x * 128;
    const int ng   = blockIdx.y;
    const int tid  = threadIdx.x;
    const int wave = tid >> 6, lane = tid & 63;
    const int lr = lane & 15, lh = lane >> 4;

    f32x4 acc[2][4];
    #pragma unroll
    for (int i = 0; i < 2; ++i)
        #pragma unroll
        for (int j = 0; j < 4; ++j)
            acc[i][j] = (f32x4){0.f, 0.f, 0.f, 0.f};

    const int srow  = tid >> 4;
    const int sslot = tid & 15;
    const _Float16* gA = hs2 + (size_t)(m0 + srow) * HIDDEN + sslot * 8;
    const _Float16* gB = Wt2 + (size_t)(ng * 64 + srow) * HIDDEN + sslot * 8;
    _Float16* lA = Asm + tid * 8;
    _Float16* lB = Bsm + tid * 8;

    for (int k0 = 0; k0 < HIDDEN; k0 += 128) {
        #pragma unroll
        for (int i = 0; i < 8; ++i)
            gload_lds16(gA + (size_t)i * 16 * HIDDEN + k0, lA + i * 2048);
        #pragma unroll
        for (int i = 0; i < 4; ++i)
            gload_lds16(gB + (size_t)i * 16 * HIDDEN + k0, lB + i * 2048);
        __syncthreads();

        #pragma unroll
        for (int kk = 0; kk < 4; ++kk) {
            half8 av[2], bv[4];
            #pragma unroll
            for (int i = 0; i < 2; ++i) {
                const int row = wave * 32 + i * 16 + lr;
                const int off = (row * 128 + kk * 32 + lh * 8) ^ ((row & 7) << 3);
                av[i] = *reinterpret_cast<const half8*>(&Asm[off]);
            }
            #pragma unroll
            for (int j = 0; j < 4; ++j) {
                const int row = j * 16 + lr;
                const int off = (row * 128 + kk * 32 + lh * 8) ^ ((row & 7) << 3);
                bv[j] = *reinterpret_cast<const half8*>(&Bsm[off]);
            }
            #pragma unroll
            for (int i = 0; i < 2; ++i)
                #pragma unroll
                for (int j = 0; j < 4; ++j)
                    acc[i][j] = __builtin_amdgcn_mfma_f32_16x16x32_f16(
                        av[i], bv[j], acc[i][j], 0, 0, 0);
        }
        __syncthreads();
    }

    // ---- epilogue. C/D: col = lr + j*16, row = wave*32 + i*16 + lh*4 + r
    if (ng < 4) {
        #pragma unroll
        for (int i = 0; i < 2; ++i)
            #pragma unroll
            for (int r = 0; r < 4; ++r) {
                const int m = m0 + wave * 32 + i * 16 + lh * 4 + r;
                const float x0 = acc[i][0][r], x1 = acc[i][1][r];
                const float c0 = cosb[(size_t)m * RR + lr];
                const float s0 = sinb[(size_t)m * RR + lr];
                const float c1 = cosb[(size_t)m * RR + 16 + lr];
                const float s1 = sinb[(size_t)m * RR + 16 + lr];
                const int sw = (m & 7) << 3;   // pre-swizzle for score staging
                const size_t rowb = (size_t)m * (NH * DD);
                const int e0 = ng * DD + lr;
                qout[rowb + (e0 ^ sw)]        = (_Float16)(x0 * c0 - x1 * s0);
                qout[rowb + ((e0 + 16) ^ sw)] = (_Float16)(x1 * c1 + x0 * s1);
                qout[rowb + ((e0 + 32) ^ sw)] = (_Float16)acc[i][2][r];
                qout[rowb + ((e0 + 48) ^ sw)] = (_Float16)acc[i][3][r];
            }
    } else if (ng == 4) {
        float g[4], bb[4];
        #pragma unroll
        for (int j = 0; j < 4; ++j) { g[j] = gamma[j * 16 + lr]; bb[j] = beta[j * 16 + lr]; }
        #pragma unroll
        for (int i = 0; i < 2; ++i)
            #pragma unroll
            for (int r = 0; r < 4; ++r) {
                float t1 = 0.f, t2 = 0.f;
                #pragma unroll
                for (int j = 0; j < 4; ++j) {
                    const float a = acc[i][j][r];
                    t1 += a; t2 += a * a;
                }
                #pragma unroll
                for (int msk = 1; msk < 16; msk <<= 1) {
                    t1 += __shfl_xor(t1, msk, 64);
                    t2 += __shfl_xor(t2, msk, 64);
                }
                const float mu  = t1 * (1.f / 64.f);
                const float var = t2 * (1.f / 64.f) - mu * mu;
                const float rs  = rsqrtf(var + LN_EPS);
                const int m = m0 + wave * 32 + i * 16 + lh * 4 + r;
                float x[4];
                #pragma unroll
                for (int j = 0; j < 4; ++j)
                    x[j] = (acc[i][j][r] - mu) * rs * g[j] + bb[j];
                const float c0 = cosb[(size_t)m * RR + lr];
                const float s0 = sinb[(size_t)m * RR + lr];
                const float c1 = cosb[(size_t)m * RR + 16 + lr];
                const float s1 = sinb[(size_t)m * RR + 16 + lr];
                const float y0 = x[0] * c0 - x[1] * s0;
                const float y1 = x[1] * c1 + x[0] * s1;
                const size_t base = (size_t)m * DD + lr;
                kout[base]      = (_Float16)y0;
                kout[base + 16] = (_Float16)y1;
                kout[base + 32] = (_Float16)x[2];
                kout[base + 48] = (_Float16)x[3];
            }
    } else {
        if (lr < NH) {
            #pragma unroll
            for (int i = 0; i < 2; ++i)
                #pragma unroll
                for (int r = 0; r < 4; ++r) {
                    const int m = m0 + wave * 32 + i * 16 + lh * 4 + r;
                    wout[(size_t)m * NH + lr] = acc[i][0][r];
                }
        }
    }
}

// ---------------------------------------------------------------------------
// score (R6 form + 2 tweaks): s = mfma(Q,K); C/D col=k, row=q; scalar stores
// (4 rows x 64B segments/inst — measured-good layout). Tweaks: (a) first
// K-frag loads issued BEFORE __syncthreads (overlap Q-stage drain); (b)
// s_setprio(1) around MFMA cluster (waves drift out of phase -> T5 regime).
// ---------------------------------------------------------------------------
__global__ __launch_bounds__(256) void score_kernel(
    const _Float16* __restrict__ qb, const _Float16* __restrict__ kb,
    const float* __restrict__ wr, float* __restrict__ out)
{
    __shared__ _Float16 Qlds[64 * 256];   // 32 KB, swizzled slots
    __shared__ float Wlds[64 * 4];        // 1 KB

    const int kc  = blockIdx.x;          // 512-col k chunk
    const int q0  = blockIdx.y * 64;
    const int b   = blockIdx.z;
    const int tid = threadIdx.x;
    const int wave = tid >> 6, lane = tid & 63;
    const int wm = wave >> 1, wn = wave & 1;
    const int lr = lane & 15, lh = lane >> 4;
    const int kbase = kc * 512;

    #pragma unroll
    for (int i = 0; i < 8; ++i) {
        const int id = i * 256 + tid;
        gload_lds16(qb + (size_t)(b * SDIM + q0 + (id >> 5)) * 256 + (id & 31) * 8,
                    Qlds + id * 8);
    }
    Wlds[tid] = wr[(size_t)(b * SDIM + q0) * NH + tid];

    const size_t krow_base = (size_t)(b * SDIM + kbase + wn * 32);
    #define LOADK(dst, st)                                                      \
        _Pragma("unroll")                                                       \
        for (int j = 0; j < 2; ++j)                                             \
            _Pragma("unroll")                                                   \
            for (int ks = 0; ks < 2; ++ks)                                      \
                dst[j][ks] = *reinterpret_cast<const half8*>(                   \
                    &kb[(krow_base + (st) * 64 + j * 16 + lr) * DD + ks * 32 + lh * 8]);

    half8 kcur[2][2], knx[2][2];
    LOADK(kcur, 0)           // issued pre-barrier: overlaps Q-staging drain

    __syncthreads();

    f32x4 wreg[2][4];
    #pragma unroll
    for (int i = 0; i < 2; ++i)
        #pragma unroll
        for (int r = 0; r < 4; ++r)
            wreg[i][r] = *reinterpret_cast<const f32x4*>(
                &Wlds[(wm * 32 + i * 16 + lh * 4 + r) * 4]);

    for (int st = 0; st < 8; ++st) {
        if (st < 7) { LOADK(knx, st + 1) }

        f32x4 o[2][2];
        #pragma unroll
        for (int i = 0; i < 2; ++i)
            #pragma unroll
            for (int j = 0; j < 2; ++j)
                o[i][j] = (f32x4){0.f, 0.f, 0.f, 0.f};

        #pragma unroll
        for (int h = 0; h < NH; ++h) {
            half8 qf[2][2];
            #pragma unroll
            for (int i = 0; i < 2; ++i)
                #pragma unroll
                for (int ks = 0; ks < 2; ++ks) {
                    const int row  = wm * 32 + i * 16 + lr;
                    const int slot = (h * 8 + ks * 4 + lh) ^ (row & 7);
                    qf[i][ks] = *reinterpret_cast<const half8*>(
                        &Qlds[row * 256 + slot * 8]);
                }
            f32x4 s[2][2];
            #pragma unroll
            for (int i = 0; i < 2; ++i)
                #pragma unroll
                for (int j = 0; j < 2; ++j)
                    s[i][j] = (f32x4){0.f, 0.f, 0.f, 0.f};
            __builtin_amdgcn_s_setprio(1);
            #pragma unroll
            for (int ks = 0; ks < 2; ++ks)
                #pragma unroll
                for (int i = 0; i < 2; ++i)
                    #pragma unroll
                    for (int j = 0; j < 2; ++j)
                        s[i][j] = __builtin_amdgcn_mfma_f32_16x16x32_f16(
                            qf[i][ks], kcur[j][ks], s[i][j], 0, 0, 0);
            __builtin_amdgcn_s_setprio(0);
            #pragma unroll
            for (int i = 0; i < 2; ++i)
                #pragma unroll
                for (int j = 0; j < 2; ++j)
                    #pragma unroll
                    for (int r = 0; r < 4; ++r)
                        o[i][j][r] += wreg[i][r][h] * fmaxf(s[i][j][r], 0.f);
        }

        #pragma unroll
        for (int i = 0; i < 2; ++i)
            #pragma unroll
            for (int r = 0; r < 4; ++r)
                #pragma unroll
                for (int j = 0; j < 2; ++j)
                    out[(size_t)(b * SDIM + q0 + wm * 32 + i * 16 + lh * 4 + r) * SDIM
                        + kbase + st * 64 + wn * 32 + j * 16 + lr] = o[i][j][r];

        #pragma unroll
        for (int j = 0; j < 2; ++j)
            #pragma unroll
            for (int ks = 0; ks < 2; ++ks)
                kcur[j][ks] = knx[j][ks];
    }
    #undef LOADK
}

// ---------------------------------------------------------------------------
extern "C" void kernel_launch(void* const* d_in, const int* in_sizes, int n_in,
                              void* d_out, int out_size, void* d_ws, size_t ws_size,
                              hipStream_t stream) {
    const float* hs    = (const float*)d_in[0];
    const float* cosb  = (const float*)d_in[1];
    const float* sinb  = (const float*)d_in[2];
    const float* Wq    = (const float*)d_in[3];
    const float* Wk    = (const float*)d_in[4];
    const float* Ww    = (const float*)d_in[5];
    const float* gamma = (const float*)d_in[6];
    const float* beta  = (const float*)d_in[7];
    float* out = (float*)d_out;

    // hs2 (33.5 MB f16) lives in d_out; dead after proj, overwritten by score.
    _Float16* hs2 = (_Float16*)d_out;

    char* wsb = (char*)d_ws;
    _Float16* qb  = (_Float16*)wsb;                                   // [M,256] f16
    _Float16* kb  = (_Float16*)(wsb + (size_t)BDIM * SDIM * 256 * 2); // [M,64] f16
    float*    ww  = (float*)(wsb + (size_t)BDIM * SDIM * 256 * 2
                                  + (size_t)BDIM * SDIM * DD * 2);
    _Float16* Wt2 = (_Float16*)(wsb + (size_t)BDIM * SDIM * 256 * 2
                                     + (size_t)BDIM * SDIM * DD * 2
                                     + (size_t)BDIM * SDIM * NH * 4);

    prep_w2<<<dim3(HIDDEN / 64, 6), 256, 0, stream>>>(Wq, Wk, Ww, Wt2);

    split_hs<<<(BDIM * SDIM * (HIDDEN / 8)) / 256, 256, 0, stream>>>(hs, hs2);

    proj_mfma<<<dim3((BDIM * SDIM) / 128, 6), 256, 0, stream>>>(
        hs2, Wt2, cosb, sinb, gamma, beta, qb, kb, ww);

    score_kernel<<<dim3(SDIM / 512, SDIM / 64, BDIM), 256, 0, stream>>>(
        qb, kb, ww, out);
}